// Round 1
// baseline (4098.309 us; speedup 1.0000x reference)
//
#include <hip/hip_runtime.h>

#define N_USERS_C 100000
#define N_ITEMS_C 40000
#define NTOT_C    140000
#define DIM_C     64

#define CDIV(a, b) (((a) + (b) - 1) / (b))

// f32 -> bf16 round-to-nearest-even
__device__ __forceinline__ unsigned short f2bf(float f) {
    unsigned u = __float_as_uint(f);
    unsigned r = (u + 0x7FFFu + ((u >> 16) & 1u)) >> 16;
    return (unsigned short)r;
}
__device__ __forceinline__ float bf2f(unsigned short h) {
    return __uint_as_float((unsigned)h << 16);
}

// LDS f32 add, workgroup scope, result unused -> ds_add_f32 (no-return)
__device__ __forceinline__ void lds_fadd(float* p, float v) {
    __hip_atomic_fetch_add(p, v, __ATOMIC_RELAXED, __HIP_MEMORY_SCOPE_WORKGROUP);
}

// ---------------------------------------------------------------------------
// Build: per-bucket histogram -> exclusive scan -> atomic-cursor partition.
// Bucket = 1<<LOG_BR consecutive rows. inter[] entry:
//   x = (row_local << 18) | col   (col < 2^18),  y = val bits.
// No row-sort inside a bucket is needed (spmm accumulates in LDS).
// ---------------------------------------------------------------------------
template <int LOG_BR>
__global__ __launch_bounds__(256) void bucket_hist(
    const int* __restrict__ rows, int* __restrict__ cnt, int nnz) {
    int i = blockIdx.x * 256 + threadIdx.x;
    if (i < nnz) atomicAdd(&cnt[rows[i] >> LOG_BR], 1);
}

// Single-block chunked exclusive scan over NB (<= ~4375) buckets.
__global__ __launch_bounds__(256) void bucket_scan(
    const int* __restrict__ cnt, int* __restrict__ start,
    int* __restrict__ cursor, int NB, int nnz) {
    __shared__ int s[256];
    __shared__ int carry_s;
    if (threadIdx.x == 0) carry_s = 0;
    __syncthreads();
    for (int base = 0; base < NB; base += 256) {
        int i = base + threadIdx.x;
        int v = (i < NB) ? cnt[i] : 0;
        s[threadIdx.x] = v;
        __syncthreads();
        #pragma unroll
        for (int off = 1; off < 256; off <<= 1) {
            int t = (threadIdx.x >= off) ? s[threadIdx.x - off] : 0;
            __syncthreads();
            s[threadIdx.x] += t;
            __syncthreads();
        }
        int tot = s[255];
        if (i < NB) {
            int ex = carry_s + s[threadIdx.x] - v;
            start[i] = ex;
            cursor[i] = ex;
        }
        __syncthreads();
        if (threadIdx.x == 0) carry_s += tot;
        __syncthreads();
    }
    if (threadIdx.x == 0) start[NB] = nnz;
}

template <int LOG_BR>
__global__ __launch_bounds__(256) void partition_edges(
    const int* __restrict__ rows, const int* __restrict__ cols,
    const float* __restrict__ vals, int* __restrict__ cursor,
    int2* __restrict__ inter, int nnz) {
    int i = blockIdx.x * 256 + threadIdx.x;
    if (i >= nnz) return;
    int r = rows[i];
    int pos = atomicAdd(&cursor[r >> LOG_BR], 1);
    inter[pos] = make_int2(((r & ((1 << LOG_BR) - 1)) << 18) | cols[i],
                           __float_as_int(vals[i]));
}

// ---------------------------------------------------------------------------
// f32 -> bf16 conversion kernels (unchanged)
// ---------------------------------------------------------------------------
__global__ __launch_bounds__(256) void to_bf16(
    const float* __restrict__ src, unsigned short* __restrict__ dst, int n4) {
    int gid = blockIdx.x * blockDim.x + threadIdx.x;
    if (gid >= n4) return;
    float4 v = ((const float4*)src)[gid];
    ushort4 o;
    o.x = f2bf(v.x); o.y = f2bf(v.y); o.z = f2bf(v.z); o.w = f2bf(v.w);
    ((ushort4*)dst)[gid] = o;
}

__global__ __launch_bounds__(256) void concat_to_bf16(
    const float* __restrict__ user_ui, const float* __restrict__ item_ui,
    unsigned short* __restrict__ dst) {
    int gid = blockIdx.x * blockDim.x + threadIdx.x;
    const int n4u = N_USERS_C * DIM_C / 4;
    const int n4  = NTOT_C * DIM_C / 4;
    if (gid >= n4) return;
    float4 v = (gid < n4u) ? ((const float4*)user_ui)[gid]
                           : ((const float4*)item_ui)[gid - n4u];
    ushort4 o;
    o.x = f2bf(v.x); o.y = f2bf(v.y); o.z = f2bf(v.z); o.w = f2bf(v.w);
    ((ushort4*)dst)[gid] = o;
}

// ---------------------------------------------------------------------------
// Bucket SpMM: one block per bucket of (1<<LOG_BR) rows. f32 accumulator tile
// in LDS; each wave streams edges unroll-8 (8 gathers in flight, no register
// accumulation dependency; ds_add_f32 is fire-and-forget, 2-way bank = free).
// Epilogue fused per MODE:
//  MODE 0: out_bf = bf16(s)
//  MODE 1: out_bf = bf16(s); acc = ego0 + s            (ui layer 1)
//  MODE 2: out_bf = bf16(s); acc += s                  (ui layer 2)
//  MODE 3: acc += s                                    (ui layer 3)
//  MODE 4: out_f32 = s; acc = acc*0.25 + s/max(||s||,eps) (ii/uu final)
// ---------------------------------------------------------------------------
template <int LOG_BR, int MODE>
__global__ __launch_bounds__(256, 8) void spmm_bkt(
    const int* __restrict__ bkt_start, const int2* __restrict__ inter,
    const unsigned short* __restrict__ x, unsigned short* __restrict__ out_bf,
    float* __restrict__ out_f32, float* __restrict__ acc,
    const float* __restrict__ ego_u, const float* __restrict__ ego_i,
    int n_rows) {
    constexpr int BR  = 1 << LOG_BR;
    constexpr int NFL = BR * DIM_C;  // floats in LDS tile
    __shared__ float sacc[NFL];
    const int tid = threadIdx.x;
    const int b = blockIdx.x;
    const int lo = bkt_start[b], hi = bkt_start[b + 1];

    float4 z4 = make_float4(0.f, 0.f, 0.f, 0.f);
    #pragma unroll
    for (int k = 0; k < NFL / 1024; ++k)
        ((float4*)sacc)[tid + 256 * k] = z4;
    __syncthreads();

    const int lane = tid & 63;
    const int wv = tid >> 6;
    // wave wv owns edge chunks [lo + r*32 + wv*8, +8)
    int j = lo + wv * 8;
    for (; j + 8 <= hi; j += 32) {
        int2 p[8];
        #pragma unroll
        for (int u = 0; u < 8; ++u) p[u] = inter[j + u];
        #pragma unroll
        for (int u = 0; u < 8; ++u) {
            int row = p[u].x >> 18;
            int col = p[u].x & 0x3FFFF;
            float xv = bf2f(x[(col << 6) + lane]);
            lds_fadd(&sacc[(row << 6) + lane], __int_as_float(p[u].y) * xv);
        }
    }
    // at most one wave has a partial chunk [j, hi)
    for (int e = j; e < hi; ++e) {
        int2 p = inter[e];
        int row = p.x >> 18;
        int col = p.x & 0x3FFFF;
        float xv = bf2f(x[(col << 6) + lane]);
        lds_fadd(&sacc[(row << 6) + lane], __int_as_float(p.y) * xv);
    }
    __syncthreads();

    // ---- fused epilogue: thread owns C consecutive floats of one row ----
    constexpr int C   = NFL / 256;   // 8 (BR=32) or 4 (BR=16)
    constexpr int TPR = DIM_C / C;   // threads per row (8 or 16)
    int r = tid / TPR;
    int grow = (b << LOG_BR) + r;
    if (grow >= n_rows) return;      // never triggers (BR divides n_rows); safety
    int gbase = b * NFL + tid * C;   // == grow*64 + d0

    float sv[C];
    #pragma unroll
    for (int k = 0; k < C; ++k) sv[k] = sacc[tid * C + k];

    if (MODE == 0 || MODE == 1 || MODE == 2) {
        ushort4 o[C / 4];
        #pragma unroll
        for (int k = 0; k < C; ++k) ((unsigned short*)o)[k] = f2bf(sv[k]);
        #pragma unroll
        for (int k = 0; k < C / 4; ++k)
            ((ushort4*)&out_bf[gbase])[k] = o[k];
    }
    if (MODE == 1) {
        const float* ego = (grow < N_USERS_C)
            ? (ego_u + gbase)
            : (ego_i + (gbase - N_USERS_C * DIM_C));
        #pragma unroll
        for (int k = 0; k < C / 4; ++k) {
            float4 e4 = ((const float4*)ego)[k];
            float4 a4 = make_float4(e4.x + sv[4 * k], e4.y + sv[4 * k + 1],
                                    e4.z + sv[4 * k + 2], e4.w + sv[4 * k + 3]);
            ((float4*)&acc[gbase])[k] = a4;
        }
    } else if (MODE == 2 || MODE == 3) {
        #pragma unroll
        for (int k = 0; k < C / 4; ++k) {
            float4 a4 = ((const float4*)&acc[gbase])[k];
            a4.x += sv[4 * k];     a4.y += sv[4 * k + 1];
            a4.z += sv[4 * k + 2]; a4.w += sv[4 * k + 3];
            ((float4*)&acc[gbase])[k] = a4;
        }
    } else if (MODE == 4) {
        float ss = 0.f;
        #pragma unroll
        for (int k = 0; k < C; ++k) ss += sv[k] * sv[k];
        #pragma unroll
        for (int off = 1; off < TPR; off <<= 1) ss += __shfl_xor(ss, off, 64);
        float inv = 1.f / fmaxf(sqrtf(ss), 1e-12f);
        #pragma unroll
        for (int k = 0; k < C / 4; ++k) {
            float4 s4 = make_float4(sv[4 * k], sv[4 * k + 1],
                                    sv[4 * k + 2], sv[4 * k + 3]);
            ((float4*)&out_f32[gbase])[k] = s4;
            float4 a4 = ((const float4*)&acc[gbase])[k];
            a4.x = a4.x * 0.25f + s4.x * inv;
            a4.y = a4.y * 0.25f + s4.y * inv;
            a4.z = a4.z * 0.25f + s4.z * inv;
            a4.w = a4.w * 0.25f + s4.w * inv;
            ((float4*)&acc[gbase])[k] = a4;
        }
    }
}

// ---------------------------------------------------------------------------

extern "C" void kernel_launch(void* const* d_in, const int* in_sizes, int n_in,
                              void* d_out, int out_size, void* d_ws, size_t ws_size,
                              hipStream_t stream) {
    const float* user_ui = (const float*)d_in[0];
    const float* item_ui = (const float*)d_in[1];
    const float* uu_emb  = (const float*)d_in[2];
    const float* ii_emb  = (const float*)d_in[3];
    const float* ui_vals = (const float*)d_in[4];
    const float* ii_vals = (const float*)d_in[5];
    const float* uu_vals = (const float*)d_in[6];
    const int* ui_rows = (const int*)d_in[7];
    const int* ui_cols = (const int*)d_in[8];
    const int* ii_rows = (const int*)d_in[9];
    const int* ii_cols = (const int*)d_in[10];
    const int* uu_rows = (const int*)d_in[11];
    const int* uu_cols = (const int*)d_in[12];
    const int nnz_ui = in_sizes[4];
    const int nnz_ii = in_sizes[5];
    const int nnz_uu = in_sizes[6];
    const int max_nnz = nnz_ui > nnz_uu ? (nnz_ui > nnz_ii ? nnz_ui : nnz_ii)
                                        : (nnz_uu > nnz_ii ? nnz_uu : nnz_ii);

    float* out    = (float*)d_out;
    float* acc    = out;                                  // [140000, 64]
    float* acc_u  = acc;
    float* acc_i  = acc + (size_t)N_USERS_C * DIM_C;
    float* out_ii = out + (size_t)NTOT_C * DIM_C;         // [40000, 64]
    float* out_uu = out_ii + (size_t)N_ITEMS_C * DIM_C;   // [100000, 64]

    // Bucket geometry: BR=32 for ui/uu, BR=16 for ii (more blocks -> occupancy).
    // All divide their row counts exactly.
    const int NB_UI = NTOT_C    >> 5;  // 4375
    const int NB_UU = N_USERS_C >> 5;  // 3125
    const int NB_II = N_ITEMS_C >> 4;  // 2500

    // Workspace carve-up (same slots/total as previous version)
    char* p = (char*)d_ws;
    int2* inter = (int2*)p;                     p += (size_t)max_nnz * sizeof(int2);
    unsigned short* buf0 = (unsigned short*)p;  p += (size_t)NTOT_C * DIM_C * sizeof(unsigned short);
    unsigned short* buf1 = (unsigned short*)p;  p += (size_t)NTOT_C * DIM_C * sizeof(unsigned short);
    int* meta = (int*)p;  // fits easily in the old rowptr+counters slot (563 KB)
    int* cnt_ui = meta;                    // counts contiguous -> single memset
    int* cnt_uu = cnt_ui + NB_UI;
    int* cnt_ii = cnt_uu + NB_UU;
    int* start_ui = cnt_ii + NB_II;
    int* start_uu = start_ui + NB_UI + 1;
    int* start_ii = start_uu + NB_UU + 1;
    int* cur_ui = start_ii + NB_II + 1;
    int* cur_uu = cur_ui + NB_UI;
    int* cur_ii = cur_uu + NB_UU;

    // zero all three count arrays in one shot
    hipMemsetAsync(cnt_ui, 0, (size_t)(NB_UI + NB_UU + NB_II) * sizeof(int), stream);

    // ==== ui chain (3 layers; acc lives in d_out head) ====
    bucket_hist<5><<<CDIV(nnz_ui, 256), 256, 0, stream>>>(ui_rows, cnt_ui, nnz_ui);
    bucket_scan<<<1, 256, 0, stream>>>(cnt_ui, start_ui, cur_ui, NB_UI, nnz_ui);
    partition_edges<5><<<CDIV(nnz_ui, 256), 256, 0, stream>>>(
        ui_rows, ui_cols, ui_vals, cur_ui, inter, nnz_ui);
    {
        int n4 = NTOT_C * DIM_C / 4;
        concat_to_bf16<<<CDIV(n4, 256), 256, 0, stream>>>(user_ui, item_ui, buf1);
    }
    spmm_bkt<5, 1><<<NB_UI, 256, 0, stream>>>(start_ui, inter, buf1, buf0,
                                              nullptr, acc, user_ui, item_ui, NTOT_C);
    spmm_bkt<5, 2><<<NB_UI, 256, 0, stream>>>(start_ui, inter, buf0, buf1,
                                              nullptr, acc, nullptr, nullptr, NTOT_C);
    spmm_bkt<5, 3><<<NB_UI, 256, 0, stream>>>(start_ui, inter, buf1, nullptr,
                                              nullptr, acc, nullptr, nullptr, NTOT_C);

    // ==== ii chain (2 layers; final fuses epilogue) ====
    bucket_hist<4><<<CDIV(nnz_ii, 256), 256, 0, stream>>>(ii_rows, cnt_ii, nnz_ii);
    bucket_scan<<<1, 256, 0, stream>>>(cnt_ii, start_ii, cur_ii, NB_II, nnz_ii);
    partition_edges<4><<<CDIV(nnz_ii, 256), 256, 0, stream>>>(
        ii_rows, ii_cols, ii_vals, cur_ii, inter, nnz_ii);
    {
        int n4 = N_ITEMS_C * DIM_C / 4;
        to_bf16<<<CDIV(n4, 256), 256, 0, stream>>>(ii_emb, buf0, n4);
    }
    spmm_bkt<4, 0><<<NB_II, 256, 0, stream>>>(start_ii, inter, buf0, buf1,
                                              nullptr, nullptr, nullptr, nullptr, N_ITEMS_C);
    spmm_bkt<4, 4><<<NB_II, 256, 0, stream>>>(start_ii, inter, buf1, nullptr,
                                              out_ii, acc_i, nullptr, nullptr, N_ITEMS_C);

    // ==== uu chain (2 layers; final fuses epilogue) ====
    bucket_hist<5><<<CDIV(nnz_uu, 256), 256, 0, stream>>>(uu_rows, cnt_uu, nnz_uu);
    bucket_scan<<<1, 256, 0, stream>>>(cnt_uu, start_uu, cur_uu, NB_UU, nnz_uu);
    partition_edges<5><<<CDIV(nnz_uu, 256), 256, 0, stream>>>(
        uu_rows, uu_cols, uu_vals, cur_uu, inter, nnz_uu);
    {
        int n4 = N_USERS_C * DIM_C / 4;
        to_bf16<<<CDIV(n4, 256), 256, 0, stream>>>(uu_emb, buf0, n4);
    }
    spmm_bkt<5, 0><<<NB_UU, 256, 0, stream>>>(start_uu, inter, buf0, buf1,
                                              nullptr, nullptr, nullptr, nullptr, N_USERS_C);
    spmm_bkt<5, 4><<<NB_UU, 256, 0, stream>>>(start_uu, inter, buf1, nullptr,
                                              out_uu, acc_u, nullptr, nullptr, N_USERS_C);
}

// Round 2
// 781.078 us; speedup vs baseline: 5.2470x; 5.2470x over previous
//
#include <hip/hip_runtime.h>

#define N_USERS_C 100000
#define N_ITEMS_C 40000
#define NTOT_C    140000
#define DIM_C     64

// f32 -> bf16 round-to-nearest-even
__device__ __forceinline__ unsigned short f2bf(float f) {
    unsigned u = __float_as_uint(f);
    unsigned r = (u + 0x7FFFu + ((u >> 16) & 1u)) >> 16;
    return (unsigned short)r;
}
__device__ __forceinline__ float bf2f(unsigned short h) {
    return __uint_as_float((unsigned)h << 16);
}

// ---------------------------------------------------------------------------
// Bucketed counting-sort CSR build (proven round-0 pipeline, unchanged).
// Bucket = contiguous range of BR rows (BR = 1<<LOG_BR), NB = ceil(n/BR) <= 256.
// inter[] entry: x = (row_local << 18) | col  (col < 2^18), y = val bits.
// ---------------------------------------------------------------------------

// P0: LDS-aggregated bucket histogram. bkt_count must be pre-zeroed.
template <int LOG_BR>
__global__ __launch_bounds__(256) void bucket_hist(
    const int* __restrict__ rows, int* __restrict__ bkt_count, int nnz, int NB) {
    __shared__ int cnt[256];
    if (threadIdx.x < NB) cnt[threadIdx.x] = 0;
    __syncthreads();
    for (int e = blockIdx.x * 256 + threadIdx.x; e < nnz; e += gridDim.x * 256)
        atomicAdd(&cnt[rows[e] >> LOG_BR], 1);
    __syncthreads();
    if (threadIdx.x < NB) {
        int c = cnt[threadIdx.x];
        if (c) atomicAdd(&bkt_count[threadIdx.x], c);
    }
}

// S0: single-block exclusive scan of NB bucket counts -> bkt_start (+sentinel),
// and init bkt_cursor.
__global__ __launch_bounds__(256) void bucket_scan(
    const int* __restrict__ bkt_count, int* __restrict__ bkt_start,
    int* __restrict__ bkt_cursor, int NB, int nnz) {
    __shared__ int s[256];
    int v = (threadIdx.x < NB) ? bkt_count[threadIdx.x] : 0;
    s[threadIdx.x] = v;
    __syncthreads();
    #pragma unroll
    for (int off = 1; off < 256; off <<= 1) {
        int t = (threadIdx.x >= off) ? s[threadIdx.x - off] : 0;
        __syncthreads();
        s[threadIdx.x] += t;
        __syncthreads();
    }
    if (threadIdx.x < NB) {
        int ex = s[threadIdx.x] - v;
        bkt_start[threadIdx.x] = ex;
        bkt_cursor[threadIdx.x] = ex;
    }
    if (threadIdx.x == 0) bkt_start[NB] = nnz;
}

// P1: block-aggregated partition into bucket-major intermediate array.
// One 4096-edge tile per block; per-bucket chunks written contiguously.
template <int LOG_BR>
__global__ __launch_bounds__(256) void partition_edges(
    const int* __restrict__ rows, const int* __restrict__ cols,
    const float* __restrict__ vals, int* __restrict__ bkt_cursor,
    int2* __restrict__ inter, int nnz) {
    __shared__ int cnt[256];
    __shared__ int base[256];
    const int tile = blockIdx.x * 4096;
    cnt[threadIdx.x] = 0;
    __syncthreads();
    int myrow[16];
    #pragma unroll
    for (int i = 0; i < 16; ++i) {
        int e = tile + i * 256 + threadIdx.x;
        int r = (e < nnz) ? rows[e] : -1;
        myrow[i] = r;
        if (r >= 0) atomicAdd(&cnt[r >> LOG_BR], 1);
    }
    __syncthreads();
    {
        int c = cnt[threadIdx.x];
        if (c) base[threadIdx.x] = atomicAdd(&bkt_cursor[threadIdx.x], c);
        cnt[threadIdx.x] = 0;  // reuse as rank counter
    }
    __syncthreads();
    #pragma unroll
    for (int i = 0; i < 16; ++i) {
        int r = myrow[i];
        if (r < 0) continue;
        int b = r >> LOG_BR;
        int rank = atomicAdd(&cnt[b], 1);
        int e = tile + i * 256 + threadIdx.x;
        int rl = r & ((1 << LOG_BR) - 1);
        inter[base[b] + rank] = make_int2((rl << 18) | cols[e],
                                          __float_as_int(vals[e]));
    }
}

// P2: one block per bucket. LDS row-hist + block scan -> rowptr + LDS cursors,
// then scatter (col,val) to final CSR positions (L2-window-local writes).
template <int LOG_BR>
__global__ __launch_bounds__(256) void bucket_to_csr(
    const int* __restrict__ bkt_start, const int2* __restrict__ inter,
    int2* __restrict__ spack, int* __restrict__ rowptr, int n_rows, int nnz) {
    const int BR = 1 << LOG_BR;
    const int C = BR / 256;  // rows per thread: 1, 2, or 4
    __shared__ int hist[BR];
    __shared__ int bsum[256];
    const int b = blockIdx.x;
    const int lo = bkt_start[b], hi = bkt_start[b + 1];
    #pragma unroll
    for (int j = 0; j < C; ++j) hist[threadIdx.x * C + j] = 0;
    __syncthreads();
    for (int i = lo + threadIdx.x; i < hi; i += 256)
        atomicAdd(&hist[inter[i].x >> 18], 1);
    __syncthreads();
    // thread-local prefix over C contiguous rows, then block scan of sums
    int loc[4];
    int sum = 0;
    #pragma unroll
    for (int j = 0; j < C; ++j) { loc[j] = sum; sum += hist[threadIdx.x * C + j]; }
    bsum[threadIdx.x] = sum;
    __syncthreads();
    #pragma unroll
    for (int off = 1; off < 256; off <<= 1) {
        int t = (threadIdx.x >= off) ? bsum[threadIdx.x - off] : 0;
        __syncthreads();
        bsum[threadIdx.x] += t;
        __syncthreads();
    }
    int texcl = bsum[threadIdx.x] - sum;
    __syncthreads();
    #pragma unroll
    for (int j = 0; j < C; ++j) {
        int r = threadIdx.x * C + j;
        int abs0 = lo + texcl + loc[j];
        int grow = (b << LOG_BR) + r;
        if (grow < n_rows) rowptr[grow] = abs0;
        hist[r] = abs0;  // absolute cursor
    }
    if (b == gridDim.x - 1 && threadIdx.x == 0) rowptr[n_rows] = nnz;
    __syncthreads();
    for (int i = lo + threadIdx.x; i < hi; i += 256) {
        int2 p = inter[i];
        int pos = atomicAdd(&hist[p.x >> 18], 1);
        spack[pos] = make_int2(p.x & 0x3FFFF, p.y);
    }
}

// ---------------------------------------------------------------------------
// f32 -> bf16 conversion kernels
// ---------------------------------------------------------------------------
__global__ __launch_bounds__(256) void to_bf16(
    const float* __restrict__ src, unsigned short* __restrict__ dst, int n4) {
    int gid = blockIdx.x * blockDim.x + threadIdx.x;
    if (gid >= n4) return;
    float4 v = ((const float4*)src)[gid];
    ushort4 o;
    o.x = f2bf(v.x); o.y = f2bf(v.y); o.z = f2bf(v.z); o.w = f2bf(v.w);
    ((ushort4*)dst)[gid] = o;
}

__global__ __launch_bounds__(256) void concat_to_bf16(
    const float* __restrict__ user_ui, const float* __restrict__ item_ui,
    unsigned short* __restrict__ dst) {
    int gid = blockIdx.x * blockDim.x + threadIdx.x;
    const int n4u = N_USERS_C * DIM_C / 4;
    const int n4  = NTOT_C * DIM_C / 4;
    if (gid >= n4) return;
    float4 v = (gid < n4u) ? ((const float4*)user_ui)[gid]
                           : ((const float4*)item_ui)[gid - n4u];
    ushort4 o;
    o.x = f2bf(v.x); o.y = f2bf(v.y); o.z = f2bf(v.z); o.w = f2bf(v.w);
    ((ushort4*)dst)[gid] = o;
}

// ---------------------------------------------------------------------------
// Gather SpMM (CSR), bf16 feature gather, f32 register accumulate.
// Wave per row; unroll-8 with batched loads -> 8 independent gathers in
// flight per wave (vs 4 before) to cover gather latency.
// MODE 0: out_bf = bf16(s)
// MODE 1: out_bf = bf16(s); acc = ego0_f32[row] + s     (ui layer 1)
// MODE 2: out_bf = bf16(s); acc += s                    (ui layer 2)
// MODE 3: acc += s                                      (ui layer 3)
// MODE 4: out_f32 = s; acc = acc*0.25 + s/max(||s||,eps) (ii/uu final)
// ---------------------------------------------------------------------------
template <int MODE>
__global__ __launch_bounds__(256) void spmm_csr(
    const int* __restrict__ rowptr, const int2* __restrict__ spack,
    const unsigned short* __restrict__ x, unsigned short* __restrict__ out_bf,
    float* __restrict__ out_f32, float* __restrict__ acc,
    const float* __restrict__ ego_u, const float* __restrict__ ego_i,
    int n_rows) {
    int w = (blockIdx.x * blockDim.x + threadIdx.x) >> 6;
    int lane = threadIdx.x & 63;
    if (w >= n_rows) return;
    int j = rowptr[w];
    int e = rowptr[w + 1];
    float sa[8];
    #pragma unroll
    for (int u = 0; u < 8; ++u) sa[u] = 0.f;

    // main: 8 edges per iteration, batched (descriptors -> gathers -> FMAs)
    for (; j + 8 <= e; j += 8) {
        int2 p[8];
        #pragma unroll
        for (int u = 0; u < 8; ++u) p[u] = spack[j + u];
        float xv[8];
        #pragma unroll
        for (int u = 0; u < 8; ++u) xv[u] = bf2f(x[(p[u].x << 6) + lane]);
        #pragma unroll
        for (int u = 0; u < 8; ++u) sa[u] += __int_as_float(p[u].y) * xv[u];
    }
    // 4-edge remainder block
    if (j + 4 <= e) {
        int2 p[4];
        #pragma unroll
        for (int u = 0; u < 4; ++u) p[u] = spack[j + u];
        float xv[4];
        #pragma unroll
        for (int u = 0; u < 4; ++u) xv[u] = bf2f(x[(p[u].x << 6) + lane]);
        #pragma unroll
        for (int u = 0; u < 4; ++u) sa[u] += __int_as_float(p[u].y) * xv[u];
        j += 4;
    }
    // singles
    for (; j < e; ++j) {
        int2 p = spack[j];
        sa[0] += __int_as_float(p.y) * bf2f(x[(p.x << 6) + lane]);
    }
    float s = ((sa[0] + sa[1]) + (sa[2] + sa[3])) +
              ((sa[4] + sa[5]) + (sa[6] + sa[7]));

    size_t idx = (size_t)w * DIM_C + lane;
    if (MODE == 0) {
        out_bf[idx] = f2bf(s);
    } else if (MODE == 1) {
        out_bf[idx] = f2bf(s);
        float ego0 = (w < N_USERS_C)
            ? ego_u[idx]
            : ego_i[(size_t)(w - N_USERS_C) * DIM_C + lane];
        acc[idx] = ego0 + s;
    } else if (MODE == 2) {
        out_bf[idx] = f2bf(s);
        acc[idx] += s;
    } else if (MODE == 3) {
        acc[idx] += s;
    } else if (MODE == 4) {
        out_f32[idx] = s;
        float ss = s * s;
        #pragma unroll
        for (int off = 32; off > 0; off >>= 1) ss += __shfl_xor(ss, off, 64);
        float denom = fmaxf(sqrtf(ss), 1e-12f);
        acc[idx] = acc[idx] * 0.25f + s / denom;
    }
}

// ---------------------------------------------------------------------------

struct BuildWs {
    int2* spack;      // [max_nnz] final CSR (col,val)
    int2* inter;      // [max_nnz] bucket-major intermediate (aliases buf0)
    int* rowptr;      // [NTOT+1]
    int* bkt_count;   // [257]
    int* bkt_start;   // [258]
    int* bkt_cursor;  // [257]
};

template <int LOG_BR>
static inline void build_csr(const int* rows, const int* cols, const float* vals,
                             int nnz, int n_rows, const BuildWs& W, hipStream_t s) {
    const int NB = (n_rows + (1 << LOG_BR) - 1) >> LOG_BR;
    hipMemsetAsync(W.bkt_count, 0, (size_t)NB * sizeof(int), s);
    bucket_hist<LOG_BR><<<512, 256, 0, s>>>(rows, W.bkt_count, nnz, NB);
    bucket_scan<<<1, 256, 0, s>>>(W.bkt_count, W.bkt_start, W.bkt_cursor, NB, nnz);
    int p1b = (nnz + 4095) / 4096;
    partition_edges<LOG_BR><<<p1b, 256, 0, s>>>(rows, cols, vals, W.bkt_cursor,
                                                W.inter, nnz);
    bucket_to_csr<LOG_BR><<<NB, 256, 0, s>>>(W.bkt_start, W.inter, W.spack,
                                             W.rowptr, n_rows, nnz);
}

template <int MODE>
static inline void run_spmm(const int* rowptr, const int2* spack,
                            const unsigned short* x, unsigned short* out_bf,
                            float* out_f32, float* acc, const float* ego_u,
                            const float* ego_i, int n_rows, hipStream_t s) {
    int blocks = (n_rows * 64 + 255) / 256;
    spmm_csr<MODE><<<blocks, 256, 0, s>>>(rowptr, spack, x, out_bf, out_f32,
                                          acc, ego_u, ego_i, n_rows);
}

extern "C" void kernel_launch(void* const* d_in, const int* in_sizes, int n_in,
                              void* d_out, int out_size, void* d_ws, size_t ws_size,
                              hipStream_t stream) {
    const float* user_ui = (const float*)d_in[0];
    const float* item_ui = (const float*)d_in[1];
    const float* uu_emb  = (const float*)d_in[2];
    const float* ii_emb  = (const float*)d_in[3];
    const float* ui_vals = (const float*)d_in[4];
    const float* ii_vals = (const float*)d_in[5];
    const float* uu_vals = (const float*)d_in[6];
    const int* ui_rows = (const int*)d_in[7];
    const int* ui_cols = (const int*)d_in[8];
    const int* ii_rows = (const int*)d_in[9];
    const int* ii_cols = (const int*)d_in[10];
    const int* uu_rows = (const int*)d_in[11];
    const int* uu_cols = (const int*)d_in[12];
    const int nnz_ui = in_sizes[4];
    const int nnz_ii = in_sizes[5];
    const int nnz_uu = in_sizes[6];
    const int max_nnz = nnz_ui > nnz_uu ? (nnz_ui > nnz_ii ? nnz_ui : nnz_ii)
                                        : (nnz_uu > nnz_ii ? nnz_uu : nnz_ii);

    float* out    = (float*)d_out;
    float* acc    = out;                                  // [140000, 64]
    float* acc_u  = acc;
    float* acc_i  = acc + (size_t)N_USERS_C * DIM_C;
    float* out_ii = out + (size_t)NTOT_C * DIM_C;         // [40000, 64]
    float* out_uu = out_ii + (size_t)N_ITEMS_C * DIM_C;   // [100000, 64]

    // Workspace carve-up (inter aliases buf0: inter is dead before buf0 is written)
    char* p = (char*)d_ws;
    BuildWs W;
    W.spack = (int2*)p;                         p += (size_t)max_nnz * sizeof(int2);
    unsigned short* buf0 = (unsigned short*)p;
    W.inter = (int2*)p;                         p += (size_t)NTOT_C * DIM_C * sizeof(unsigned short);
    unsigned short* buf1 = (unsigned short*)p;  p += (size_t)NTOT_C * DIM_C * sizeof(unsigned short);
    W.rowptr     = (int*)p;                     p += (size_t)(NTOT_C + 1) * sizeof(int);
    W.bkt_count  = (int*)p;                     p += 257 * sizeof(int);
    W.bkt_start  = (int*)p;                     p += 258 * sizeof(int);
    W.bkt_cursor = (int*)p;                     p += 257 * sizeof(int);

    // ==== ui chain (3 layers; acc lives in d_out head); BR=1024, NB=137 ====
    build_csr<10>(ui_rows, ui_cols, ui_vals, nnz_ui, NTOT_C, W, stream);
    {
        int n4 = NTOT_C * DIM_C / 4;
        concat_to_bf16<<<(n4 + 255) / 256, 256, 0, stream>>>(user_ui, item_ui, buf1);
    }
    // L1: s = S*ego0(buf1); buf0 = bf16(s) (overwrites dead inter); acc = ego0 + s
    run_spmm<1>(W.rowptr, W.spack, buf1, buf0, nullptr, acc, user_ui, item_ui,
                NTOT_C, stream);
    // L2: s = S*ego1(buf0); buf1 = bf16(s); acc += s
    run_spmm<2>(W.rowptr, W.spack, buf0, buf1, nullptr, acc, nullptr, nullptr,
                NTOT_C, stream);
    // L3: s = S*ego2(buf1); acc += s
    run_spmm<3>(W.rowptr, W.spack, buf1, nullptr, nullptr, acc, nullptr, nullptr,
                NTOT_C, stream);

    // ==== ii chain (2 layers; final fuses epilogue); BR=256, NB=157 ====
    build_csr<8>(ii_rows, ii_cols, ii_vals, nnz_ii, N_ITEMS_C, W, stream);
    {
        int n4 = N_ITEMS_C * DIM_C / 4;
        to_bf16<<<(n4 + 255) / 256, 256, 0, stream>>>(ii_emb, buf0, n4);
    }
    run_spmm<0>(W.rowptr, W.spack, buf0, buf1, nullptr, nullptr, nullptr, nullptr,
                N_ITEMS_C, stream);
    run_spmm<4>(W.rowptr, W.spack, buf1, nullptr, out_ii, acc_i, nullptr, nullptr,
                N_ITEMS_C, stream);

    // ==== uu chain (2 layers; final fuses epilogue); BR=512, NB=196 ====
    build_csr<9>(uu_rows, uu_cols, uu_vals, nnz_uu, N_USERS_C, W, stream);
    {
        int n4 = N_USERS_C * DIM_C / 4;
        to_bf16<<<(n4 + 255) / 256, 256, 0, stream>>>(uu_emb, buf0, n4);
    }
    run_spmm<0>(W.rowptr, W.spack, buf0, buf1, nullptr, nullptr, nullptr, nullptr,
                N_USERS_C, stream);
    run_spmm<4>(W.rowptr, W.spack, buf1, nullptr, out_uu, acc_u, nullptr, nullptr,
                N_USERS_C, stream);
}

// Round 3
// 712.092 us; speedup vs baseline: 5.7553x; 1.0969x over previous
//
#include <hip/hip_runtime.h>

#define N_USERS_C 100000
#define N_ITEMS_C 40000
#define NTOT_C    140000
#define DIM_C     64

// f32 -> bf16 round-to-nearest-even
__device__ __forceinline__ unsigned short f2bf(float f) {
    unsigned u = __float_as_uint(f);
    unsigned r = (u + 0x7FFFu + ((u >> 16) & 1u)) >> 16;
    return (unsigned short)r;
}
__device__ __forceinline__ float bf2f(unsigned short h) {
    return __uint_as_float((unsigned)h << 16);
}

// ---------------------------------------------------------------------------
// Bucketed counting-sort CSR build (proven round-0 pipeline, unchanged).
// Bucket = contiguous range of BR rows (BR = 1<<LOG_BR), NB = ceil(n/BR) <= 256.
// inter[] entry: x = (row_local << 18) | col  (col < 2^18), y = val bits.
// ---------------------------------------------------------------------------

// P0: LDS-aggregated bucket histogram. bkt_count must be pre-zeroed.
template <int LOG_BR>
__global__ __launch_bounds__(256) void bucket_hist(
    const int* __restrict__ rows, int* __restrict__ bkt_count, int nnz, int NB) {
    __shared__ int cnt[256];
    if (threadIdx.x < NB) cnt[threadIdx.x] = 0;
    __syncthreads();
    for (int e = blockIdx.x * 256 + threadIdx.x; e < nnz; e += gridDim.x * 256)
        atomicAdd(&cnt[rows[e] >> LOG_BR], 1);
    __syncthreads();
    if (threadIdx.x < NB) {
        int c = cnt[threadIdx.x];
        if (c) atomicAdd(&bkt_count[threadIdx.x], c);
    }
}

// S0: single-block exclusive scan of NB bucket counts -> bkt_start (+sentinel),
// and init bkt_cursor.
__global__ __launch_bounds__(256) void bucket_scan(
    const int* __restrict__ bkt_count, int* __restrict__ bkt_start,
    int* __restrict__ bkt_cursor, int NB, int nnz) {
    __shared__ int s[256];
    int v = (threadIdx.x < NB) ? bkt_count[threadIdx.x] : 0;
    s[threadIdx.x] = v;
    __syncthreads();
    #pragma unroll
    for (int off = 1; off < 256; off <<= 1) {
        int t = (threadIdx.x >= off) ? s[threadIdx.x - off] : 0;
        __syncthreads();
        s[threadIdx.x] += t;
        __syncthreads();
    }
    if (threadIdx.x < NB) {
        int ex = s[threadIdx.x] - v;
        bkt_start[threadIdx.x] = ex;
        bkt_cursor[threadIdx.x] = ex;
    }
    if (threadIdx.x == 0) bkt_start[NB] = nnz;
}

// P1: block-aggregated partition into bucket-major intermediate array.
// One 4096-edge tile per block; per-bucket chunks written contiguously.
template <int LOG_BR>
__global__ __launch_bounds__(256) void partition_edges(
    const int* __restrict__ rows, const int* __restrict__ cols,
    const float* __restrict__ vals, int* __restrict__ bkt_cursor,
    int2* __restrict__ inter, int nnz) {
    __shared__ int cnt[256];
    __shared__ int base[256];
    const int tile = blockIdx.x * 4096;
    cnt[threadIdx.x] = 0;
    __syncthreads();
    int myrow[16];
    #pragma unroll
    for (int i = 0; i < 16; ++i) {
        int e = tile + i * 256 + threadIdx.x;
        int r = (e < nnz) ? rows[e] : -1;
        myrow[i] = r;
        if (r >= 0) atomicAdd(&cnt[r >> LOG_BR], 1);
    }
    __syncthreads();
    {
        int c = cnt[threadIdx.x];
        if (c) base[threadIdx.x] = atomicAdd(&bkt_cursor[threadIdx.x], c);
        cnt[threadIdx.x] = 0;  // reuse as rank counter
    }
    __syncthreads();
    #pragma unroll
    for (int i = 0; i < 16; ++i) {
        int r = myrow[i];
        if (r < 0) continue;
        int b = r >> LOG_BR;
        int rank = atomicAdd(&cnt[b], 1);
        int e = tile + i * 256 + threadIdx.x;
        int rl = r & ((1 << LOG_BR) - 1);
        inter[base[b] + rank] = make_int2((rl << 18) | cols[e],
                                          __float_as_int(vals[e]));
    }
}

// P2: one block per bucket. LDS row-hist + block scan -> rowptr + LDS cursors,
// then scatter (col,val) to final CSR positions (L2-window-local writes).
template <int LOG_BR>
__global__ __launch_bounds__(256) void bucket_to_csr(
    const int* __restrict__ bkt_start, const int2* __restrict__ inter,
    int2* __restrict__ spack, int* __restrict__ rowptr, int n_rows, int nnz) {
    const int BR = 1 << LOG_BR;
    const int C = BR / 256;  // rows per thread: 1, 2, or 4
    __shared__ int hist[BR];
    __shared__ int bsum[256];
    const int b = blockIdx.x;
    const int lo = bkt_start[b], hi = bkt_start[b + 1];
    #pragma unroll
    for (int j = 0; j < C; ++j) hist[threadIdx.x * C + j] = 0;
    __syncthreads();
    for (int i = lo + threadIdx.x; i < hi; i += 256)
        atomicAdd(&hist[inter[i].x >> 18], 1);
    __syncthreads();
    // thread-local prefix over C contiguous rows, then block scan of sums
    int loc[4];
    int sum = 0;
    #pragma unroll
    for (int j = 0; j < C; ++j) { loc[j] = sum; sum += hist[threadIdx.x * C + j]; }
    bsum[threadIdx.x] = sum;
    __syncthreads();
    #pragma unroll
    for (int off = 1; off < 256; off <<= 1) {
        int t = (threadIdx.x >= off) ? bsum[threadIdx.x - off] : 0;
        __syncthreads();
        bsum[threadIdx.x] += t;
        __syncthreads();
    }
    int texcl = bsum[threadIdx.x] - sum;
    __syncthreads();
    #pragma unroll
    for (int j = 0; j < C; ++j) {
        int r = threadIdx.x * C + j;
        int abs0 = lo + texcl + loc[j];
        int grow = (b << LOG_BR) + r;
        if (grow < n_rows) rowptr[grow] = abs0;
        hist[r] = abs0;  // absolute cursor
    }
    if (b == gridDim.x - 1 && threadIdx.x == 0) rowptr[n_rows] = nnz;
    __syncthreads();
    for (int i = lo + threadIdx.x; i < hi; i += 256) {
        int2 p = inter[i];
        int pos = atomicAdd(&hist[p.x >> 18], 1);
        spack[pos] = make_int2(p.x & 0x3FFFF, p.y);
    }
}

// ---------------------------------------------------------------------------
// f32 -> bf16 conversion kernels
// ---------------------------------------------------------------------------
__global__ __launch_bounds__(256) void to_bf16(
    const float* __restrict__ src, unsigned short* __restrict__ dst, int n4) {
    int gid = blockIdx.x * blockDim.x + threadIdx.x;
    if (gid >= n4) return;
    float4 v = ((const float4*)src)[gid];
    ushort4 o;
    o.x = f2bf(v.x); o.y = f2bf(v.y); o.z = f2bf(v.z); o.w = f2bf(v.w);
    ((ushort4*)dst)[gid] = o;
}

__global__ __launch_bounds__(256) void concat_to_bf16(
    const float* __restrict__ user_ui, const float* __restrict__ item_ui,
    unsigned short* __restrict__ dst) {
    int gid = blockIdx.x * blockDim.x + threadIdx.x;
    const int n4u = N_USERS_C * DIM_C / 4;
    const int n4  = NTOT_C * DIM_C / 4;
    if (gid >= n4) return;
    float4 v = (gid < n4u) ? ((const float4*)user_ui)[gid]
                           : ((const float4*)item_ui)[gid - n4u];
    ushort4 o;
    o.x = f2bf(v.x); o.y = f2bf(v.y); o.z = f2bf(v.z); o.w = f2bf(v.w);
    ((ushort4*)dst)[gid] = o;
}

// ---------------------------------------------------------------------------
// Gather SpMM (CSR): 2 rows per wave, 32 lanes per row, 2 dims per lane.
// Each wave carries two independent edge streams (halves), unroll-4 each,
// with software-pipelined descriptor prefetch: gathers for iteration i wait
// only on descriptors loaded during iteration i-1. Invalid (tail) slots
// multiply by 0 and gather from a fixed hot line (no random traffic).
// MODE 0: out_bf = bf16(s)
// MODE 1: out_bf = bf16(s); acc = ego0_f32[row] + s     (ui layer 1)
// MODE 2: out_bf = bf16(s); acc += s                    (ui layer 2)
// MODE 3: acc += s                                      (ui layer 3)
// MODE 4: out_f32 = s; acc = acc*0.25 + s/max(||s||,eps) (ii/uu final)
// Requires n_rows even (140000 / 40000 / 100000 all are).
// ---------------------------------------------------------------------------
template <int MODE>
__global__ __launch_bounds__(256) void spmm_csr2(
    const int* __restrict__ rowptr, const int2* __restrict__ spack,
    const unsigned short* __restrict__ x, unsigned short* __restrict__ out_bf,
    float* __restrict__ out_f32, float* __restrict__ acc,
    const float* __restrict__ ego_u, const float* __restrict__ ego_i,
    int n_rows, int nnz) {
    const int wpair = (blockIdx.x * 256 + threadIdx.x) >> 6;  // one row pair
    const int lane  = threadIdx.x & 63;
    const int l     = lane & 31;          // lane within half
    const int row   = wpair * 2 + (lane >> 5);

    int j = rowptr[row];
    int e = rowptr[row + 1];
    int rem = e - j;                       // uniform within half
    int orem = __shfl_xor(rem, 32, 64);    // other half's remaining
    int mrem = rem > orem ? rem : orem;    // uniform across wave

    const unsigned* __restrict__ xw = (const unsigned*)x;  // ushort2 words
    const int last = nnz - 1;

    float s0x = 0.f, s0y = 0.f, s1x = 0.f, s1y = 0.f;
    float s2x = 0.f, s2y = 0.f, s3x = 0.f, s3y = 0.f;

    if (mrem > 0) {
        int base = j;
        int2 p0 = spack[min(base + 0, last)];
        int2 p1 = spack[min(base + 1, last)];
        int2 p2 = spack[min(base + 2, last)];
        int2 p3 = spack[min(base + 3, last)];
        for (;;) {
            // gathers for current descriptors (tail slots -> hot line 0)
            unsigned g0 = xw[(0 < rem) ? ((p0.x << 5) + l) : l];
            unsigned g1 = xw[(1 < rem) ? ((p1.x << 5) + l) : l];
            unsigned g2 = xw[(2 < rem) ? ((p2.x << 5) + l) : l];
            unsigned g3 = xw[(3 < rem) ? ((p3.x << 5) + l) : l];
            // prefetch next iteration's descriptors (stay in flight thru FMAs)
            int nb = base + 4;
            int2 q0 = spack[min(nb + 0, last)];
            int2 q1 = spack[min(nb + 1, last)];
            int2 q2 = spack[min(nb + 2, last)];
            int2 q3 = spack[min(nb + 3, last)];
            float v0 = (0 < rem) ? __int_as_float(p0.y) : 0.f;
            float v1 = (1 < rem) ? __int_as_float(p1.y) : 0.f;
            float v2 = (2 < rem) ? __int_as_float(p2.y) : 0.f;
            float v3 = (3 < rem) ? __int_as_float(p3.y) : 0.f;
            s0x += v0 * __uint_as_float(g0 << 16);
            s0y += v0 * __uint_as_float(g0 & 0xFFFF0000u);
            s1x += v1 * __uint_as_float(g1 << 16);
            s1y += v1 * __uint_as_float(g1 & 0xFFFF0000u);
            s2x += v2 * __uint_as_float(g2 << 16);
            s2y += v2 * __uint_as_float(g2 & 0xFFFF0000u);
            s3x += v3 * __uint_as_float(g3 << 16);
            s3y += v3 * __uint_as_float(g3 & 0xFFFF0000u);
            mrem -= 4;
            if (mrem <= 0) break;
            rem -= 4;
            base = nb;
            p0 = q0; p1 = q1; p2 = q2; p3 = q3;
        }
    }
    float sx = (s0x + s1x) + (s2x + s3x);
    float sy = (s0y + s1y) + (s2y + s3y);

    const size_t idx2 = (size_t)row * 32 + l;  // float2 / ushort2 units
    if (MODE == 0 || MODE == 1 || MODE == 2) {
        ushort2 o;
        o.x = f2bf(sx);
        o.y = f2bf(sy);
        ((ushort2*)out_bf)[idx2] = o;
    }
    if (MODE == 1) {
        float2 e2 = (row < N_USERS_C)
            ? ((const float2*)ego_u)[idx2]
            : ((const float2*)ego_i)[(size_t)(row - N_USERS_C) * 32 + l];
        ((float2*)acc)[idx2] = make_float2(e2.x + sx, e2.y + sy);
    } else if (MODE == 2 || MODE == 3) {
        float2 a = ((float2*)acc)[idx2];
        ((float2*)acc)[idx2] = make_float2(a.x + sx, a.y + sy);
    } else if (MODE == 4) {
        ((float2*)out_f32)[idx2] = make_float2(sx, sy);
        float ss = sx * sx + sy * sy;
        #pragma unroll
        for (int off = 1; off < 32; off <<= 1) ss += __shfl_xor(ss, off, 64);
        float denom = fmaxf(sqrtf(ss), 1e-12f);
        float2 a = ((float2*)acc)[idx2];
        a.x = a.x * 0.25f + sx / denom;
        a.y = a.y * 0.25f + sy / denom;
        ((float2*)acc)[idx2] = a;
    }
}

// ---------------------------------------------------------------------------

struct BuildWs {
    int2* spack;      // [max_nnz] final CSR (col,val)
    int2* inter;      // [max_nnz] bucket-major intermediate (aliases buf0)
    int* rowptr;      // [NTOT+1]
    int* bkt_count;   // [257]
    int* bkt_start;   // [258]
    int* bkt_cursor;  // [257]
};

template <int LOG_BR>
static inline void build_csr(const int* rows, const int* cols, const float* vals,
                             int nnz, int n_rows, const BuildWs& W, hipStream_t s) {
    const int NB = (n_rows + (1 << LOG_BR) - 1) >> LOG_BR;
    hipMemsetAsync(W.bkt_count, 0, (size_t)NB * sizeof(int), s);
    bucket_hist<LOG_BR><<<512, 256, 0, s>>>(rows, W.bkt_count, nnz, NB);
    bucket_scan<<<1, 256, 0, s>>>(W.bkt_count, W.bkt_start, W.bkt_cursor, NB, nnz);
    int p1b = (nnz + 4095) / 4096;
    partition_edges<LOG_BR><<<p1b, 256, 0, s>>>(rows, cols, vals, W.bkt_cursor,
                                                W.inter, nnz);
    bucket_to_csr<LOG_BR><<<NB, 256, 0, s>>>(W.bkt_start, W.inter, W.spack,
                                             W.rowptr, n_rows, nnz);
}

template <int MODE>
static inline void run_spmm(const int* rowptr, const int2* spack,
                            const unsigned short* x, unsigned short* out_bf,
                            float* out_f32, float* acc, const float* ego_u,
                            const float* ego_i, int n_rows, int nnz, hipStream_t s) {
    // one wave per row pair: n_rows*32 threads total (n_rows even, /8 exact)
    int blocks = (n_rows * 32 + 255) / 256;
    spmm_csr2<MODE><<<blocks, 256, 0, s>>>(rowptr, spack, x, out_bf, out_f32,
                                           acc, ego_u, ego_i, n_rows, nnz);
}

extern "C" void kernel_launch(void* const* d_in, const int* in_sizes, int n_in,
                              void* d_out, int out_size, void* d_ws, size_t ws_size,
                              hipStream_t stream) {
    const float* user_ui = (const float*)d_in[0];
    const float* item_ui = (const float*)d_in[1];
    const float* uu_emb  = (const float*)d_in[2];
    const float* ii_emb  = (const float*)d_in[3];
    const float* ui_vals = (const float*)d_in[4];
    const float* ii_vals = (const float*)d_in[5];
    const float* uu_vals = (const float*)d_in[6];
    const int* ui_rows = (const int*)d_in[7];
    const int* ui_cols = (const int*)d_in[8];
    const int* ii_rows = (const int*)d_in[9];
    const int* ii_cols = (const int*)d_in[10];
    const int* uu_rows = (const int*)d_in[11];
    const int* uu_cols = (const int*)d_in[12];
    const int nnz_ui = in_sizes[4];
    const int nnz_ii = in_sizes[5];
    const int nnz_uu = in_sizes[6];
    const int max_nnz = nnz_ui > nnz_uu ? (nnz_ui > nnz_ii ? nnz_ui : nnz_ii)
                                        : (nnz_uu > nnz_ii ? nnz_uu : nnz_ii);

    float* out    = (float*)d_out;
    float* acc    = out;                                  // [140000, 64]
    float* acc_u  = acc;
    float* acc_i  = acc + (size_t)N_USERS_C * DIM_C;
    float* out_ii = out + (size_t)NTOT_C * DIM_C;         // [40000, 64]
    float* out_uu = out_ii + (size_t)N_ITEMS_C * DIM_C;   // [100000, 64]

    // Workspace carve-up (inter aliases buf0: inter is dead before buf0 is written)
    char* p = (char*)d_ws;
    BuildWs W;
    W.spack = (int2*)p;                         p += (size_t)max_nnz * sizeof(int2);
    unsigned short* buf0 = (unsigned short*)p;
    W.inter = (int2*)p;                         p += (size_t)NTOT_C * DIM_C * sizeof(unsigned short);
    unsigned short* buf1 = (unsigned short*)p;  p += (size_t)NTOT_C * DIM_C * sizeof(unsigned short);
    W.rowptr     = (int*)p;                     p += (size_t)(NTOT_C + 1) * sizeof(int);
    W.bkt_count  = (int*)p;                     p += 257 * sizeof(int);
    W.bkt_start  = (int*)p;                     p += 258 * sizeof(int);
    W.bkt_cursor = (int*)p;                     p += 257 * sizeof(int);

    // ==== ui chain (3 layers; acc lives in d_out head); BR=1024, NB=137 ====
    build_csr<10>(ui_rows, ui_cols, ui_vals, nnz_ui, NTOT_C, W, stream);
    {
        int n4 = NTOT_C * DIM_C / 4;
        concat_to_bf16<<<(n4 + 255) / 256, 256, 0, stream>>>(user_ui, item_ui, buf1);
    }
    // L1: s = S*ego0(buf1); buf0 = bf16(s) (overwrites dead inter); acc = ego0 + s
    run_spmm<1>(W.rowptr, W.spack, buf1, buf0, nullptr, acc, user_ui, item_ui,
                NTOT_C, nnz_ui, stream);
    // L2: s = S*ego1(buf0); buf1 = bf16(s); acc += s
    run_spmm<2>(W.rowptr, W.spack, buf0, buf1, nullptr, acc, nullptr, nullptr,
                NTOT_C, nnz_ui, stream);
    // L3: s = S*ego2(buf1); acc += s
    run_spmm<3>(W.rowptr, W.spack, buf1, nullptr, nullptr, acc, nullptr, nullptr,
                NTOT_C, nnz_ui, stream);

    // ==== ii chain (2 layers; final fuses epilogue); BR=256, NB=157 ====
    build_csr<8>(ii_rows, ii_cols, ii_vals, nnz_ii, N_ITEMS_C, W, stream);
    {
        int n4 = N_ITEMS_C * DIM_C / 4;
        to_bf16<<<(n4 + 255) / 256, 256, 0, stream>>>(ii_emb, buf0, n4);
    }
    run_spmm<0>(W.rowptr, W.spack, buf0, buf1, nullptr, nullptr, nullptr, nullptr,
                N_ITEMS_C, nnz_ii, stream);
    run_spmm<4>(W.rowptr, W.spack, buf1, nullptr, out_ii, acc_i, nullptr, nullptr,
                N_ITEMS_C, nnz_ii, stream);

    // ==== uu chain (2 layers; final fuses epilogue); BR=512, NB=196 ====
    build_csr<9>(uu_rows, uu_cols, uu_vals, nnz_uu, N_USERS_C, W, stream);
    {
        int n4 = N_USERS_C * DIM_C / 4;
        to_bf16<<<(n4 + 255) / 256, 256, 0, stream>>>(uu_emb, buf0, n4);
    }
    run_spmm<0>(W.rowptr, W.spack, buf0, buf1, nullptr, nullptr, nullptr, nullptr,
                N_USERS_C, nnz_uu, stream);
    run_spmm<4>(W.rowptr, W.spack, buf1, nullptr, out_uu, acc_u, nullptr, nullptr,
                N_USERS_C, nnz_uu, stream);
}

// Round 4
// 641.095 us; speedup vs baseline: 6.3927x; 1.1107x over previous
//
#include <hip/hip_runtime.h>

#define N_USERS_C 100000
#define N_ITEMS_C 40000
#define NTOT_C    140000
#define DIM_C     64

// f32 -> bf16 round-to-nearest-even
__device__ __forceinline__ unsigned short f2bf(float f) {
    unsigned u = __float_as_uint(f);
    unsigned r = (u + 0x7FFFu + ((u >> 16) & 1u)) >> 16;
    return (unsigned short)r;
}

// ---------------------------------------------------------------------------
// Bucketed counting-sort CSR build. Bucket = 1<<LOG_BR consecutive rows,
// NB <= 256. inter[] entry: x = (row_local << 18) | col (col < 2^18), y = val.
// row_off/col_off let two edge lists build one block-diagonal matrix.
// ---------------------------------------------------------------------------

// P0: LDS-aggregated bucket histogram. bkt_count pre-zeroed.
template <int LOG_BR>
__global__ __launch_bounds__(256) void bucket_hist(
    const int* __restrict__ rows, int row_off, int* __restrict__ bkt_count,
    int nnz, int NB) {
    __shared__ int cnt[256];
    if (threadIdx.x < NB) cnt[threadIdx.x] = 0;
    __syncthreads();
    for (int e = blockIdx.x * 256 + threadIdx.x; e < nnz; e += gridDim.x * 256)
        atomicAdd(&cnt[(rows[e] + row_off) >> LOG_BR], 1);
    __syncthreads();
    if (threadIdx.x < NB) {
        int c = cnt[threadIdx.x];
        if (c) atomicAdd(&bkt_count[threadIdx.x], c);
    }
}

// S0: single-block exclusive scan of NB (<=256) bucket counts.
__global__ __launch_bounds__(256) void bucket_scan(
    const int* __restrict__ bkt_count, int* __restrict__ bkt_start,
    int* __restrict__ bkt_cursor, int NB, int nnz) {
    __shared__ int s[256];
    int v = (threadIdx.x < NB) ? bkt_count[threadIdx.x] : 0;
    s[threadIdx.x] = v;
    __syncthreads();
    #pragma unroll
    for (int off = 1; off < 256; off <<= 1) {
        int t = (threadIdx.x >= off) ? s[threadIdx.x - off] : 0;
        __syncthreads();
        s[threadIdx.x] += t;
        __syncthreads();
    }
    if (threadIdx.x < NB) {
        int ex = s[threadIdx.x] - v;
        bkt_start[threadIdx.x] = ex;
        bkt_cursor[threadIdx.x] = ex;
    }
    if (threadIdx.x == 0) bkt_start[NB] = nnz;
}

// P1: block-aggregated partition into bucket-major intermediate array.
template <int LOG_BR>
__global__ __launch_bounds__(256) void partition_edges(
    const int* __restrict__ rows, const int* __restrict__ cols,
    const float* __restrict__ vals, int row_off, int col_off,
    int* __restrict__ bkt_cursor, int2* __restrict__ inter, int nnz) {
    __shared__ int cnt[256];
    __shared__ int base[256];
    const int tile = blockIdx.x * 4096;
    cnt[threadIdx.x] = 0;
    __syncthreads();
    int myrow[16];
    #pragma unroll
    for (int i = 0; i < 16; ++i) {
        int e = tile + i * 256 + threadIdx.x;
        int r = (e < nnz) ? (rows[e] + row_off) : -1;
        myrow[i] = r;
        if (r >= 0) atomicAdd(&cnt[r >> LOG_BR], 1);
    }
    __syncthreads();
    {
        int c = cnt[threadIdx.x];
        if (c) base[threadIdx.x] = atomicAdd(&bkt_cursor[threadIdx.x], c);
        cnt[threadIdx.x] = 0;  // reuse as rank counter
    }
    __syncthreads();
    #pragma unroll
    for (int i = 0; i < 16; ++i) {
        int r = myrow[i];
        if (r < 0) continue;
        int b = r >> LOG_BR;
        int rank = atomicAdd(&cnt[b], 1);
        int e = tile + i * 256 + threadIdx.x;
        int rl = r & ((1 << LOG_BR) - 1);
        inter[base[b] + rank] = make_int2((rl << 18) | (cols[e] + col_off),
                                          __float_as_int(vals[e]));
    }
}

// P2: one block per bucket -> rowptr + row-sorted spack.
template <int LOG_BR>
__global__ __launch_bounds__(256) void bucket_to_csr(
    const int* __restrict__ bkt_start, const int2* __restrict__ inter,
    int2* __restrict__ spack, int* __restrict__ rowptr, int n_rows, int nnz) {
    const int BR = 1 << LOG_BR;
    const int C = BR / 256;
    __shared__ int hist[BR];
    __shared__ int bsum[256];
    const int b = blockIdx.x;
    const int lo = bkt_start[b], hi = bkt_start[b + 1];
    #pragma unroll
    for (int j = 0; j < C; ++j) hist[threadIdx.x * C + j] = 0;
    __syncthreads();
    for (int i = lo + threadIdx.x; i < hi; i += 256)
        atomicAdd(&hist[inter[i].x >> 18], 1);
    __syncthreads();
    int loc[4];
    int sum = 0;
    #pragma unroll
    for (int j = 0; j < C; ++j) { loc[j] = sum; sum += hist[threadIdx.x * C + j]; }
    bsum[threadIdx.x] = sum;
    __syncthreads();
    #pragma unroll
    for (int off = 1; off < 256; off <<= 1) {
        int t = (threadIdx.x >= off) ? bsum[threadIdx.x - off] : 0;
        __syncthreads();
        bsum[threadIdx.x] += t;
        __syncthreads();
    }
    int texcl = bsum[threadIdx.x] - sum;
    __syncthreads();
    #pragma unroll
    for (int j = 0; j < C; ++j) {
        int r = threadIdx.x * C + j;
        int abs0 = lo + texcl + loc[j];
        int grow = (b << LOG_BR) + r;
        if (grow < n_rows) rowptr[grow] = abs0;
        hist[r] = abs0;
    }
    if (b == gridDim.x - 1 && threadIdx.x == 0) rowptr[n_rows] = nnz;
    __syncthreads();
    for (int i = lo + threadIdx.x; i < hi; i += 256) {
        int2 p = inter[i];
        int pos = atomicAdd(&hist[p.x >> 18], 1);
        spack[pos] = make_int2(p.x & 0x3FFFF, p.y);
    }
}

// ---------------------------------------------------------------------------
// f32 -> bf16: dst[0..n4A) <- A, dst[n4A..n4tot) <- B  (float4 granularity)
// ---------------------------------------------------------------------------
__global__ __launch_bounds__(256) void concat2_to_bf16(
    const float* __restrict__ A, const float* __restrict__ B, int n4A,
    int n4tot, unsigned short* __restrict__ dst) {
    int gid = blockIdx.x * blockDim.x + threadIdx.x;
    if (gid >= n4tot) return;
    float4 v = (gid < n4A) ? ((const float4*)A)[gid] : ((const float4*)B)[gid - n4A];
    ushort4 o;
    o.x = f2bf(v.x); o.y = f2bf(v.y); o.z = f2bf(v.z); o.w = f2bf(v.w);
    ((ushort4*)dst)[gid] = o;
}

// ---------------------------------------------------------------------------
// Gather SpMM (CSR): 4 rows per wave, 16 lanes per row, 4 dims per lane.
// 4 independent edge streams/wave, unroll-4 each, software-pipelined
// descriptor prefetch. Tail slots gather a hot line and multiply by 0.
// MODE 0: out_bf = bf16(s)
// MODE 1: out_bf = bf16(s); acc = ego0 + s                (ui layer 1)
// MODE 2: out_bf = bf16(s); acc += s                      (ui layer 2)
// MODE 3: acc += s                                        (ui layer 3)
// MODE 4: out_f32 = s; acc = acc*0.25 + s/max(||s||,eps)  (separate ii/uu final)
// MODE 5: same as 4 but block-diagonal cat row->acc row mapping
// Requires n_rows % 16 == 0 (140000/100000/40000 all qualify).
// ---------------------------------------------------------------------------
template <int MODE>
__global__ __launch_bounds__(256) void spmm_csr4(
    const int* __restrict__ rowptr, const int2* __restrict__ spack,
    const unsigned short* __restrict__ x, unsigned short* __restrict__ out_bf,
    float* __restrict__ out_f32, float* __restrict__ acc,
    const float* __restrict__ ego_u, const float* __restrict__ ego_i,
    int n_rows, int nnz) {
    const int wq   = (blockIdx.x * 256 + threadIdx.x) >> 6;  // row quad id
    const int lane = threadIdx.x & 63;
    const int l    = lane & 15;            // lane within row group
    const int row  = wq * 4 + (lane >> 4);

    int j = rowptr[row];
    int e = rowptr[row + 1];
    int rem = e - j;                              // uniform within 16-lane group
    int m1 = max(rem, __shfl_xor(rem, 16, 64));
    int mrem = max(m1, __shfl_xor(m1, 32, 64));   // uniform across wave

    const uint2* __restrict__ xq = (const uint2*)x;  // 4 bf16 per uint2
    const int last = nnz - 1;

    float4 sa[4];
    #pragma unroll
    for (int u = 0; u < 4; ++u) sa[u] = make_float4(0.f, 0.f, 0.f, 0.f);

    if (mrem > 0) {
        int base = j;
        int2 p[4];
        #pragma unroll
        for (int u = 0; u < 4; ++u) p[u] = spack[min(base + u, last)];
        for (;;) {
            uint2 g[4];
            #pragma unroll
            for (int u = 0; u < 4; ++u)
                g[u] = xq[(u < rem) ? ((p[u].x << 4) + l) : l];
            int nb = base + 4;
            int2 q[4];
            #pragma unroll
            for (int u = 0; u < 4; ++u) q[u] = spack[min(nb + u, last)];
            #pragma unroll
            for (int u = 0; u < 4; ++u) {
                float v = (u < rem) ? __int_as_float(p[u].y) : 0.f;
                sa[u].x += v * __uint_as_float(g[u].x << 16);
                sa[u].y += v * __uint_as_float(g[u].x & 0xFFFF0000u);
                sa[u].z += v * __uint_as_float(g[u].y << 16);
                sa[u].w += v * __uint_as_float(g[u].y & 0xFFFF0000u);
            }
            mrem -= 4;
            if (mrem <= 0) break;
            rem -= 4;
            base = nb;
            #pragma unroll
            for (int u = 0; u < 4; ++u) p[u] = q[u];
        }
    }
    float4 s;
    s.x = (sa[0].x + sa[1].x) + (sa[2].x + sa[3].x);
    s.y = (sa[0].y + sa[1].y) + (sa[2].y + sa[3].y);
    s.z = (sa[0].z + sa[1].z) + (sa[2].z + sa[3].z);
    s.w = (sa[0].w + sa[1].w) + (sa[2].w + sa[3].w);

    const size_t idx4 = (size_t)row * 16 + l;  // float4 / ushort4 units
    if (MODE == 0 || MODE == 1 || MODE == 2) {
        ushort4 o;
        o.x = f2bf(s.x); o.y = f2bf(s.y); o.z = f2bf(s.z); o.w = f2bf(s.w);
        ((ushort4*)out_bf)[idx4] = o;
    }
    if (MODE == 1) {
        float4 e4 = (row < N_USERS_C)
            ? ((const float4*)ego_u)[idx4]
            : ((const float4*)ego_i)[(size_t)(row - N_USERS_C) * 16 + l];
        ((float4*)acc)[idx4] = make_float4(e4.x + s.x, e4.y + s.y,
                                           e4.z + s.z, e4.w + s.w);
    } else if (MODE == 2 || MODE == 3) {
        float4 a = ((const float4*)acc)[idx4];
        ((float4*)acc)[idx4] = make_float4(a.x + s.x, a.y + s.y,
                                           a.z + s.z, a.w + s.w);
    } else if (MODE == 4 || MODE == 5) {
        ((float4*)out_f32)[idx4] = s;
        float ss = s.x * s.x + s.y * s.y + s.z * s.z + s.w * s.w;
        #pragma unroll
        for (int off = 1; off < 16; off <<= 1) ss += __shfl_xor(ss, off, 64);
        float inv = 1.f / fmaxf(sqrtf(ss), 1e-12f);
        size_t aidx = idx4;
        if (MODE == 5) {
            int arow = (row < N_ITEMS_C) ? (N_USERS_C + row) : (row - N_ITEMS_C);
            aidx = (size_t)arow * 16 + l;
        }
        float4 a = ((const float4*)acc)[aidx];
        a.x = a.x * 0.25f + s.x * inv;
        a.y = a.y * 0.25f + s.y * inv;
        a.z = a.z * 0.25f + s.z * inv;
        a.w = a.w * 0.25f + s.w * inv;
        ((float4*)acc)[aidx] = a;
    }
}

// ---------------------------------------------------------------------------

template <int MODE>
static inline void run_spmm(const int* rowptr, const int2* spack,
                            const unsigned short* x, unsigned short* out_bf,
                            float* out_f32, float* acc, const float* ego_u,
                            const float* ego_i, int n_rows, int nnz, hipStream_t s) {
    spmm_csr4<MODE><<<n_rows / 16, 256, 0, s>>>(rowptr, spack, x, out_bf, out_f32,
                                                acc, ego_u, ego_i, n_rows, nnz);
}

extern "C" void kernel_launch(void* const* d_in, const int* in_sizes, int n_in,
                              void* d_out, int out_size, void* d_ws, size_t ws_size,
                              hipStream_t stream) {
    const float* user_ui = (const float*)d_in[0];
    const float* item_ui = (const float*)d_in[1];
    const float* uu_emb  = (const float*)d_in[2];
    const float* ii_emb  = (const float*)d_in[3];
    const float* ui_vals = (const float*)d_in[4];
    const float* ii_vals = (const float*)d_in[5];
    const float* uu_vals = (const float*)d_in[6];
    const int* ui_rows = (const int*)d_in[7];
    const int* ui_cols = (const int*)d_in[8];
    const int* ii_rows = (const int*)d_in[9];
    const int* ii_cols = (const int*)d_in[10];
    const int* uu_rows = (const int*)d_in[11];
    const int* uu_cols = (const int*)d_in[12];
    const int nnz_ui = in_sizes[4];
    const int nnz_ii = in_sizes[5];
    const int nnz_uu = in_sizes[6];
    const int nnz_cat = nnz_ii + nnz_uu;

    float* out    = (float*)d_out;
    float* acc    = out;                                  // [140000, 64]
    float* acc_u  = acc;
    float* acc_i  = acc + (size_t)N_USERS_C * DIM_C;
    float* out_ii = out + (size_t)NTOT_C * DIM_C;         // [40000, 64]
    float* out_uu = out_ii + (size_t)N_ITEMS_C * DIM_C;   // [100000, 64]
    float* out_cat = out_ii;  // out_ii then out_uu are contiguous -> cat rows map 1:1

    const size_t buf_bytes = (size_t)NTOT_C * DIM_C * sizeof(unsigned short);
    const size_t sp_ui  = (size_t)nnz_ui * sizeof(int2);
    const size_t sp_cat = (size_t)nnz_cat * sizeof(int2);
    const size_t meta_bytes = ((size_t)(NTOT_C + 1) + 1024) * sizeof(int);

    // cat layout: [A: spack][B: inter / buf0][C: buf1][meta]
    size_t slotA = sp_cat > sp_ui ? sp_cat : sp_ui;
    size_t slotB = slotA > buf_bytes ? slotA : buf_bytes;
    bool use_cat = ws_size >= slotA + slotB + buf_bytes + meta_bytes;
    if (!use_cat) {  // fallback: separate ii/uu chains (round-3 footprint)
        size_t mx = sp_ui;
        if ((size_t)nnz_ii * sizeof(int2) > mx) mx = (size_t)nnz_ii * sizeof(int2);
        if ((size_t)nnz_uu * sizeof(int2) > mx) mx = (size_t)nnz_uu * sizeof(int2);
        slotA = mx;
        slotB = buf_bytes;  // inter (<= mx <= buf_bytes? mx=12MB < 17.92MB ok) aliases buf0
    }

    char* p = (char*)d_ws;
    int2* spack = (int2*)p;                     p += slotA;
    int2* inter = (int2*)p;
    unsigned short* buf0 = (unsigned short*)p;  p += slotB;
    unsigned short* buf1 = (unsigned short*)p;  p += buf_bytes;
    int* rowptr     = (int*)p;
    int* bkt_count  = rowptr + (NTOT_C + 1);
    int* bkt_start  = bkt_count + 257;
    int* bkt_cursor = bkt_start + 258;

    const int n4tot = NTOT_C * DIM_C / 4;
    const int n4u   = N_USERS_C * DIM_C / 4;
    const int n4i   = N_ITEMS_C * DIM_C / 4;

    // ==== ui chain (3 layers; acc lives in d_out head); BR=1024, NB=137 ====
    {
        const int NB = (NTOT_C + 1023) >> 10;
        hipMemsetAsync(bkt_count, 0, (size_t)NB * sizeof(int), stream);
        bucket_hist<10><<<512, 256, 0, stream>>>(ui_rows, 0, bkt_count, nnz_ui, NB);
        bucket_scan<<<1, 256, 0, stream>>>(bkt_count, bkt_start, bkt_cursor, NB, nnz_ui);
        partition_edges<10><<<(nnz_ui + 4095) / 4096, 256, 0, stream>>>(
            ui_rows, ui_cols, ui_vals, 0, 0, bkt_cursor, inter, nnz_ui);
        bucket_to_csr<10><<<NB, 256, 0, stream>>>(bkt_start, inter, spack, rowptr,
                                                  NTOT_C, nnz_ui);
    }
    concat2_to_bf16<<<(n4tot + 255) / 256, 256, 0, stream>>>(user_ui, item_ui,
                                                             n4u, n4tot, buf1);
    run_spmm<1>(rowptr, spack, buf1, buf0, nullptr, acc, user_ui, item_ui,
                NTOT_C, nnz_ui, stream);
    run_spmm<2>(rowptr, spack, buf0, buf1, nullptr, acc, nullptr, nullptr,
                NTOT_C, nnz_ui, stream);
    run_spmm<3>(rowptr, spack, buf1, nullptr, nullptr, acc, nullptr, nullptr,
                NTOT_C, nnz_ui, stream);

    if (use_cat) {
        // ==== fused ii+uu chain: block-diagonal diag(S_ii, S_uu) on
        // [ii_emb; uu_emb]; 2 layers; final epilogue remaps rows ====
        const int NB = (NTOT_C + 1023) >> 10;
        hipMemsetAsync(bkt_count, 0, (size_t)NB * sizeof(int), stream);
        bucket_hist<10><<<512, 256, 0, stream>>>(ii_rows, 0, bkt_count, nnz_ii, NB);
        bucket_hist<10><<<512, 256, 0, stream>>>(uu_rows, N_ITEMS_C, bkt_count,
                                                 nnz_uu, NB);
        bucket_scan<<<1, 256, 0, stream>>>(bkt_count, bkt_start, bkt_cursor, NB,
                                           nnz_cat);
        partition_edges<10><<<(nnz_ii + 4095) / 4096, 256, 0, stream>>>(
            ii_rows, ii_cols, ii_vals, 0, 0, bkt_cursor, inter, nnz_ii);
        partition_edges<10><<<(nnz_uu + 4095) / 4096, 256, 0, stream>>>(
            uu_rows, uu_cols, uu_vals, N_ITEMS_C, N_ITEMS_C, bkt_cursor, inter,
            nnz_uu);
        bucket_to_csr<10><<<NB, 256, 0, stream>>>(bkt_start, inter, spack, rowptr,
                                                  NTOT_C, nnz_cat);
        concat2_to_bf16<<<(n4tot + 255) / 256, 256, 0, stream>>>(ii_emb, uu_emb,
                                                                 n4i, n4tot, buf1);
        run_spmm<0>(rowptr, spack, buf1, buf0, nullptr, nullptr, nullptr, nullptr,
                    NTOT_C, nnz_cat, stream);
        run_spmm<5>(rowptr, spack, buf0, nullptr, out_cat, acc, nullptr, nullptr,
                    NTOT_C, nnz_cat, stream);
    } else {
        // ==== fallback: separate chains (round-3 structure) ====
        {  // ii: BR=256, NB=157
            const int NB = (N_ITEMS_C + 255) >> 8;
            hipMemsetAsync(bkt_count, 0, (size_t)NB * sizeof(int), stream);
            bucket_hist<8><<<512, 256, 0, stream>>>(ii_rows, 0, bkt_count, nnz_ii, NB);
            bucket_scan<<<1, 256, 0, stream>>>(bkt_count, bkt_start, bkt_cursor,
                                               NB, nnz_ii);
            partition_edges<8><<<(nnz_ii + 4095) / 4096, 256, 0, stream>>>(
                ii_rows, ii_cols, ii_vals, 0, 0, bkt_cursor, inter, nnz_ii);
            bucket_to_csr<8><<<NB, 256, 0, stream>>>(bkt_start, inter, spack,
                                                     rowptr, N_ITEMS_C, nnz_ii);
        }
        concat2_to_bf16<<<(n4i + 255) / 256, 256, 0, stream>>>(ii_emb, ii_emb,
                                                               n4i, n4i, buf0);
        run_spmm<0>(rowptr, spack, buf0, buf1, nullptr, nullptr, nullptr, nullptr,
                    N_ITEMS_C, nnz_ii, stream);
        run_spmm<4>(rowptr, spack, buf1, nullptr, out_ii, acc_i, nullptr, nullptr,
                    N_ITEMS_C, nnz_ii, stream);
        {  // uu: BR=512, NB=196
            const int NB = (N_USERS_C + 511) >> 9;
            hipMemsetAsync(bkt_count, 0, (size_t)NB * sizeof(int), stream);
            bucket_hist<9><<<512, 256, 0, stream>>>(uu_rows, 0, bkt_count, nnz_uu, NB);
            bucket_scan<<<1, 256, 0, stream>>>(bkt_count, bkt_start, bkt_cursor,
                                               NB, nnz_uu);
            partition_edges<9><<<(nnz_uu + 4095) / 4096, 256, 0, stream>>>(
                uu_rows, uu_cols, uu_vals, 0, 0, bkt_cursor, inter, nnz_uu);
            bucket_to_csr<9><<<NB, 256, 0, stream>>>(bkt_start, inter, spack,
                                                     rowptr, N_USERS_C, nnz_uu);
        }
        concat2_to_bf16<<<(n4u + 255) / 256, 256, 0, stream>>>(uu_emb, uu_emb,
                                                               n4u, n4u, buf0);
        run_spmm<0>(rowptr, spack, buf0, buf1, nullptr, nullptr, nullptr, nullptr,
                    N_USERS_C, nnz_uu, stream);
        run_spmm<4>(rowptr, spack, buf1, nullptr, out_uu, acc_u, nullptr, nullptr,
                    N_USERS_C, nnz_uu, stream);
    }
}